// Round 1
// baseline (588.354 us; speedup 1.0000x reference)
//
#include <hip/hip_runtime.h>
#include <cstdint>
#include <cstddef>

typedef __attribute__((ext_vector_type(8))) short short8;
typedef __attribute__((ext_vector_type(4))) short short4v;
typedef __attribute__((ext_vector_type(4))) float f32x4;

#define DEV static __device__ __forceinline__

DEV short f2bf(float f) {
    unsigned u = __builtin_bit_cast(unsigned, f);
    unsigned r = (u + 0x7fffu + ((u >> 16) & 1u)) >> 16;
    return (short)r;
}

DEV void gld16(const void* g, void* l) {
    __builtin_amdgcn_global_load_lds((const __attribute__((address_space(1))) void*)g,
                                     (__attribute__((address_space(3))) void*)l, 16, 0, 0);
}

#define MFMA(c, a, b) asm volatile("v_mfma_f32_16x16x32_bf16 %0, %1, %2, %0" : "+v"(c) : "v"(a), "v"(b))

// ---------------- weight fp32 -> bf16 convert (all 6 weights, one launch) ----------------
__global__ __launch_bounds__(256) void cvt_weights(
    const float* __restrict__ wq, const float* __restrict__ wk,
    const float* __restrict__ wv, const float* __restrict__ wo,
    const float* __restrict__ w1, const float* __restrict__ w2,
    short* __restrict__ dst) {
    long long gid = (long long)blockIdx.x * 256 + threadIdx.x;
    long long i4 = gid * 4;                       // element index (4 per thread)
    const float* src; long long loc;
    if (i4 < (4LL << 20)) {                       // four 1M-element weights
        int s = (int)(i4 >> 20);
        src = (s == 0) ? wq : (s == 1) ? wk : (s == 2) ? wv : wo;
        loc = i4 & ((1LL << 20) - 1);
    } else {                                      // two 4M-element weights
        long long r = i4 - (4LL << 20);
        int s = (int)(r >> 22);
        src = s ? w2 : w1;
        loc = r & ((1LL << 22) - 1);
    }
    float4 v = *(const float4*)(src + loc);
    short4v o;
    o.x = f2bf(v.x); o.y = f2bf(v.y); o.z = f2bf(v.z); o.w = f2bf(v.w);
    *(short4v*)(dst + i4) = o;
}

// ---------------- LayerNorm (D=1024), fp32 in -> bf16 out ----------------
__global__ __launch_bounds__(256) void ln_bf16(const float* __restrict__ x,
                                               const float* __restrict__ g,
                                               const float* __restrict__ bt,
                                               short* __restrict__ out) {
    int row = blockIdx.x;
    const float4* xr = (const float4*)(x + (size_t)row * 1024);
    float4 v = xr[threadIdx.x];
    float s  = v.x + v.y + v.z + v.w;
    float s2 = v.x*v.x + v.y*v.y + v.z*v.z + v.w*v.w;
    #pragma unroll
    for (int m = 1; m < 64; m <<= 1) { s += __shfl_xor(s, m); s2 += __shfl_xor(s2, m); }
    __shared__ float red[8];
    int wid = threadIdx.x >> 6;
    if ((threadIdx.x & 63) == 0) { red[wid] = s; red[4 + wid] = s2; }
    __syncthreads();
    s  = red[0] + red[1] + red[2] + red[3];
    s2 = red[4] + red[5] + red[6] + red[7];
    float mu  = s * (1.0f / 1024.0f);
    float var = fmaxf(s2 * (1.0f / 1024.0f) - mu * mu, 0.0f);
    float rs  = rsqrtf(var + 1e-5f);
    float4 gv = ((const float4*)g)[threadIdx.x];
    float4 bv = ((const float4*)bt)[threadIdx.x];
    short4v o;
    o.x = f2bf((v.x - mu) * rs * gv.x + bv.x);
    o.y = f2bf((v.y - mu) * rs * gv.y + bv.y);
    o.z = f2bf((v.z - mu) * rs * gv.z + bv.z);
    o.w = f2bf((v.w - mu) * rs * gv.w + bv.w);
    *(short4v*)(out + (size_t)row * 1024 + (size_t)threadIdx.x * 4) = o;
}

// ---------------- GEMM: C[M,N] = A[M,K] * B[N,K]^T, bf16 in, fp32 acc ----------------
// MODE 0: bf16 out. MODE 1: fp32 out = acc + resid. MODE 2: bf16 out = gelu(acc).
// 128x128 tile, BK=32, 256 threads = 4 waves (2x2), each wave 64x64 = 4x4 frags.
template<int MODE>
__global__ __launch_bounds__(256) void gemm_bt(const short* __restrict__ A,
                                               const short* __restrict__ B,
                                               void* __restrict__ out,
                                               const float* __restrict__ resid,
                                               int M, int N, int K) {
    __shared__ short lA[2][128 * 32];
    __shared__ short lB[2][128 * 32];
    int tid = threadIdx.x;
    int nbn = N >> 7;
    int bm = blockIdx.x / nbn, bn = blockIdx.x % nbn;
    int row0 = bm << 7, col0 = bn << 7;
    int wid = tid >> 6, lane = tid & 63;
    int wm = wid >> 1, wn = wid & 1;
    int lr = lane & 15, lg = lane >> 4;

    f32x4 acc[4][4] = {};

    auto stage = [&](int buf, int kst) {
        const short* Ab = A + (size_t)row0 * K + kst * 32;
        const short* Bb = B + (size_t)col0 * K + kst * 32;
        #pragma unroll
        for (int c = 0; c < 2; ++c) {
            int idx = c * 256 + tid;
            int r = idx >> 2, sp = idx & 3;
            int sl = sp ^ ((r >> 1) & 3);      // inverse-swizzled source column
            gld16(Ab + (size_t)r * K + sl * 8, &lA[buf][idx * 8]);
            gld16(Bb + (size_t)r * K + sl * 8, &lB[buf][idx * 8]);
        }
    };

    int NK = K >> 5;
    stage(0, 0);
    __syncthreads();
    for (int ks = 0; ks < NK; ++ks) {
        int cur = ks & 1;
        if (ks + 1 < NK) stage(cur ^ 1, ks + 1);
        const short* pa = lA[cur];
        const short* pb = lB[cur];
        short8 af[4], bf[4];
        #pragma unroll
        for (int f = 0; f < 4; ++f) {
            int ra = wm * 64 + f * 16 + lr;
            af[f] = *(const short8*)(pa + ra * 32 + ((lg ^ ((ra >> 1) & 3)) << 3));
            int rb = wn * 64 + f * 16 + lr;
            bf[f] = *(const short8*)(pb + rb * 32 + ((lg ^ ((rb >> 1) & 3)) << 3));
        }
        #pragma unroll
        for (int i = 0; i < 4; ++i)
            #pragma unroll
            for (int j = 0; j < 4; ++j)
                MFMA(acc[i][j], af[i], bf[j]);
        __syncthreads();
    }
    asm volatile("s_nop 7\n\ts_nop 7");

    int orow0 = row0 + wm * 64, ocol0 = col0 + wn * 64;
    #pragma unroll
    for (int i = 0; i < 4; ++i)
        #pragma unroll
        for (int j = 0; j < 4; ++j)
            #pragma unroll
            for (int r = 0; r < 4; ++r) {
                int gr = orow0 + i * 16 + lg * 4 + r;
                int gc = ocol0 + j * 16 + lr;
                size_t off = (size_t)gr * N + gc;
                float v = acc[i][j][r];
                if constexpr (MODE == 0) {
                    ((short*)out)[off] = f2bf(v);
                } else if constexpr (MODE == 1) {
                    ((float*)out)[off] = v + resid[off];
                } else {
                    float t = 0.5f * v * (1.0f + erff(v * 0.70710678118f));
                    ((short*)out)[off] = f2bf(t);
                }
            }
}

// ---------------- Flash attention ----------------
// Q [8192,1024] bf16 (rows b*2048+t, cols h*64+d), K same layout, Vt [1024,8192] (rows h*64+d, cols b*2048+s)
// grid = (B*H) * (T/128); block = 256 = 4 waves, each wave 32 q-rows. KV tile = 64.
__global__ __launch_bounds__(256) void attn(const short* __restrict__ Q,
                                            const short* __restrict__ K,
                                            const short* __restrict__ Vt,
                                            short* __restrict__ O) {
    __shared__ short lK[64 * 64];
    __shared__ short lV[64 * 64];
    __shared__ short lP[4][32 * 64];
    int tid = threadIdx.x;
    int qt = blockIdx.x & 15;
    int bh = blockIdx.x >> 4;
    int b = bh >> 4, h = bh & 15;
    int wid = tid >> 6, lane = tid & 63;
    int lr = lane & 15, lg = lane >> 4;
    int q0 = qt * 128 + wid * 32;

    short8 qf[2][2];
    #pragma unroll
    for (int fm = 0; fm < 2; ++fm)
        #pragma unroll
        for (int kb = 0; kb < 2; ++kb) {
            size_t roff = (size_t)(b * 2048 + q0 + fm * 16 + lr) * 1024 + h * 64 + kb * 32 + lg * 8;
            qf[fm][kb] = *(const short8*)(Q + roff);
        }

    f32x4 oacc[2][4] = {};
    float mrow[2][4], lrs[2][4];
    #pragma unroll
    for (int fm = 0; fm < 2; ++fm)
        #pragma unroll
        for (int r = 0; r < 4; ++r) { mrow[fm][r] = -1e30f; lrs[fm][r] = 0.0f; }

    const short* Kb = K + (size_t)(b * 2048) * 1024 + h * 64;
    const short* Vb = Vt + (size_t)(h * 64) * 8192 + b * 2048;
    short* Pw = lP[wid];

    for (int st = 0; st < 32; ++st) {
        #pragma unroll
        for (int c = 0; c < 2; ++c) {
            int idx = c * 256 + tid;
            int r = idx >> 3, sp = idx & 7;
            int sl = sp ^ (r & 7);
            gld16(Kb + (size_t)(st * 64 + r) * 1024 + sl * 8, &lK[idx * 8]);
            gld16(Vb + (size_t)r * 8192 + st * 64 + sl * 8, &lV[idx * 8]);
        }
        __syncthreads();

        f32x4 sc[2][4] = {};
        #pragma unroll
        for (int kb = 0; kb < 2; ++kb) {
            short8 kf[4];
            #pragma unroll
            for (int fn = 0; fn < 4; ++fn) {
                int kr = fn * 16 + lr;
                kf[fn] = *(const short8*)(lK + kr * 64 + (((kb * 4 + lg) ^ (kr & 7)) << 3));
            }
            #pragma unroll
            for (int fm = 0; fm < 2; ++fm)
                #pragma unroll
                for (int fn = 0; fn < 4; ++fn)
                    MFMA(sc[fm][fn], qf[fm][kb], kf[fn]);
        }
        asm volatile("s_nop 7\n\ts_nop 7");

        #pragma unroll
        for (int fm = 0; fm < 2; ++fm)
            #pragma unroll
            for (int r = 0; r < 4; ++r) {
                float v0 = sc[fm][0][r] * 0.125f;
                float v1 = sc[fm][1][r] * 0.125f;
                float v2 = sc[fm][2][r] * 0.125f;
                float v3 = sc[fm][3][r] * 0.125f;
                float tm = fmaxf(fmaxf(v0, v1), fmaxf(v2, v3));
                #pragma unroll
                for (int m = 1; m < 16; m <<= 1) tm = fmaxf(tm, __shfl_xor(tm, m));
                float mo = mrow[fm][r];
                float mn = fmaxf(mo, tm);
                float al = __expf(mo - mn);
                float p0 = __expf(v0 - mn), p1 = __expf(v1 - mn);
                float p2 = __expf(v2 - mn), p3 = __expf(v3 - mn);
                float ps = p0 + p1 + p2 + p3;
                #pragma unroll
                for (int m = 1; m < 16; m <<= 1) ps += __shfl_xor(ps, m);
                lrs[fm][r] = lrs[fm][r] * al + ps;
                mrow[fm][r] = mn;
                sc[fm][0][r] = p0; sc[fm][1][r] = p1; sc[fm][2][r] = p2; sc[fm][3][r] = p3;
                #pragma unroll
                for (int fn = 0; fn < 4; ++fn) oacc[fm][fn][r] *= al;
            }

        #pragma unroll
        for (int fm = 0; fm < 2; ++fm)
            #pragma unroll
            for (int fn = 0; fn < 4; ++fn)
                #pragma unroll
                for (int r = 0; r < 4; ++r) {
                    int pr = fm * 16 + lg * 4 + r;
                    int off = (pr * 64 + fn * 16 + lr) ^ ((pr & 7) << 3);
                    Pw[off] = f2bf(sc[fm][fn][r]);
                }

        #pragma unroll
        for (int kb = 0; kb < 2; ++kb) {
            short8 pa[2], vf[4];
            #pragma unroll
            for (int fm = 0; fm < 2; ++fm) {
                int pr = fm * 16 + lr;
                pa[fm] = *(const short8*)(Pw + pr * 64 + (((kb * 4 + lg) ^ (pr & 7)) << 3));
            }
            #pragma unroll
            for (int fn = 0; fn < 4; ++fn) {
                int vr = fn * 16 + lr;
                vf[fn] = *(const short8*)(lV + vr * 64 + (((kb * 4 + lg) ^ (vr & 7)) << 3));
            }
            #pragma unroll
            for (int fm = 0; fm < 2; ++fm)
                #pragma unroll
                for (int fn = 0; fn < 4; ++fn)
                    MFMA(oacc[fm][fn], pa[fm], vf[fn]);
        }
        __syncthreads();
    }
    asm volatile("s_nop 7\n\ts_nop 7");

    #pragma unroll
    for (int fm = 0; fm < 2; ++fm)
        #pragma unroll
        for (int r = 0; r < 4; ++r) {
            float inv = 1.0f / lrs[fm][r];
            #pragma unroll
            for (int fn = 0; fn < 4; ++fn) {
                size_t off = (size_t)(b * 2048 + q0 + fm * 16 + lg * 4 + r) * 1024 + h * 64 + fn * 16 + lr;
                O[off] = f2bf(oacc[fm][fn][r] * inv);
            }
        }
}

// ---------------- launch ----------------
extern "C" void kernel_launch(void* const* d_in, const int* in_sizes, int n_in,
                              void* d_out, int out_size, void* d_ws, size_t ws_size,
                              hipStream_t stream) {
    const float* x   = (const float*)d_in[0];
    const float* ctx = (const float*)d_in[1];
    const float* Wq  = (const float*)d_in[2];
    const float* Wk  = (const float*)d_in[3];
    const float* Wv  = (const float*)d_in[4];
    const float* Wo  = (const float*)d_in[5];
    const float* W1  = (const float*)d_in[6];
    const float* W2  = (const float*)d_in[7];
    const float* g1  = (const float*)d_in[8];
    const float* b1  = (const float*)d_in[9];
    const float* gc  = (const float*)d_in[10];
    const float* bc  = (const float*)d_in[11];
    const float* g2  = (const float*)d_in[12];
    const float* b2  = (const float*)d_in[13];

    char* ws = (char*)d_ws;
    // byte offsets
    const size_t OFF_W  = 0;                    // 12.58M bf16 = 25,165,824 B
    const size_t OFF_XN = 25165824;             // 16 MB each activation
    const size_t OFF_CN = OFF_XN + 16777216;
    const size_t OFF_QB = OFF_CN + 16777216;
    const size_t OFF_KB = OFF_QB + 16777216;
    const size_t OFF_VT = OFF_KB + 16777216;
    const size_t OFF_X2 = OFF_VT + 16777216;    // fp32, 32 MB
    const size_t OFF_F1 = OFF_X2 + 33554432;    // bf16, 64 MB

    short* Wb = (short*)(ws + OFF_W);
    short* XN = (short*)(ws + OFF_XN);
    short* CN = (short*)(ws + OFF_CN);
    short* QB = (short*)(ws + OFF_QB);
    short* KB = (short*)(ws + OFF_KB);
    short* VT = (short*)(ws + OFF_VT);
    float* X2 = (float*)(ws + OFF_X2);
    short* F1 = (short*)(ws + OFF_F1);
    short* OB = XN;   // reuse: xn dead after Q projection
    short* H  = CN;   // reuse: cn dead after K/V projections

    const size_t WQo = 0, WKo = 1048576, WVo = 2097152, WOo = 3145728;
    const size_t W1o = 4194304, W2o = 8388608;

    cvt_weights<<<12288, 256, 0, stream>>>(Wq, Wk, Wv, Wo, W1, W2, Wb);
    ln_bf16<<<8192, 256, 0, stream>>>(x, g1, b1, XN);
    ln_bf16<<<8192, 256, 0, stream>>>(ctx, gc, bc, CN);
    gemm_bt<0><<<512, 256, 0, stream>>>(XN, Wb + WQo, QB, nullptr, 8192, 1024, 1024);
    gemm_bt<0><<<512, 256, 0, stream>>>(CN, Wb + WKo, KB, nullptr, 8192, 1024, 1024);
    gemm_bt<0><<<512, 256, 0, stream>>>(Wb + WVo, CN, VT, nullptr, 1024, 8192, 1024); // Vt = Wv * cn^T
    attn<<<1024, 256, 0, stream>>>(QB, KB, VT, OB);
    gemm_bt<1><<<512, 256, 0, stream>>>(OB, Wb + WOo, X2, x, 8192, 1024, 1024);
    ln_bf16<<<8192, 256, 0, stream>>>(X2, g2, b2, H);
    gemm_bt<2><<<2048, 256, 0, stream>>>(H, Wb + W1o, F1, nullptr, 8192, 4096, 1024);
    gemm_bt<1><<<512, 256, 0, stream>>>(F1, Wb + W2o, (float*)d_out, X2, 8192, 1024, 4096);
}

// Round 2
// 490.051 us; speedup vs baseline: 1.2006x; 1.2006x over previous
//
#include <hip/hip_runtime.h>
#include <cstdint>
#include <cstddef>

typedef __attribute__((ext_vector_type(8))) short short8;
typedef __attribute__((ext_vector_type(4))) short short4v;
typedef __attribute__((ext_vector_type(4))) float f32x4;
typedef __attribute__((ext_vector_type(2))) unsigned uint2v;

#define DEV static __device__ __forceinline__

DEV short f2bf(float f) {
    unsigned u = __builtin_bit_cast(unsigned, f);
    unsigned r = (u + 0x7fffu + ((u >> 16) & 1u)) >> 16;
    return (short)r;
}

DEV unsigned cvt_pk_bf16(float a, float b) {   // low16 = a, high16 = b (RNE)
    unsigned r;
    asm("v_cvt_pk_bf16_f32 %0, %1, %2" : "=v"(r) : "v"(a), "v"(b));
    return r;
}

DEV float exp2_hw(float x) {                   // v_exp_f32 IS exp2
    float r;
    asm("v_exp_f32 %0, %1" : "=v"(r) : "v"(x));
    return r;
}

DEV void gld16(const void* g, void* l) {
    __builtin_amdgcn_global_load_lds((const __attribute__((address_space(1))) void*)g,
                                     (__attribute__((address_space(3))) void*)l, 16, 0, 0);
}

#define MFMA(c, a, b) asm volatile("v_mfma_f32_16x16x32_bf16 %0, %1, %2, %0" : "+v"(c) : "v"(a), "v"(b))

// ---------------- weight fp32 -> bf16 convert (all 6 weights, one launch) ----------------
__global__ __launch_bounds__(256) void cvt_weights(
    const float* __restrict__ wq, const float* __restrict__ wk,
    const float* __restrict__ wv, const float* __restrict__ wo,
    const float* __restrict__ w1, const float* __restrict__ w2,
    short* __restrict__ dst) {
    long long gid = (long long)blockIdx.x * 256 + threadIdx.x;
    long long i4 = gid * 4;
    const float* src; long long loc;
    if (i4 < (4LL << 20)) {
        int s = (int)(i4 >> 20);
        src = (s == 0) ? wq : (s == 1) ? wk : (s == 2) ? wv : wo;
        loc = i4 & ((1LL << 20) - 1);
    } else {
        long long r = i4 - (4LL << 20);
        int s = (int)(r >> 22);
        src = s ? w2 : w1;
        loc = r & ((1LL << 22) - 1);
    }
    float4 v = *(const float4*)(src + loc);
    short4v o;
    o.x = f2bf(v.x); o.y = f2bf(v.y); o.z = f2bf(v.z); o.w = f2bf(v.w);
    *(short4v*)(dst + i4) = o;
}

// ---------------- LayerNorm (D=1024), fp32 in -> bf16 out ----------------
__global__ __launch_bounds__(256) void ln_bf16(const float* __restrict__ x,
                                               const float* __restrict__ g,
                                               const float* __restrict__ bt,
                                               short* __restrict__ out) {
    int row = blockIdx.x;
    const float4* xr = (const float4*)(x + (size_t)row * 1024);
    float4 v = xr[threadIdx.x];
    float s  = v.x + v.y + v.z + v.w;
    float s2 = v.x*v.x + v.y*v.y + v.z*v.z + v.w*v.w;
    #pragma unroll
    for (int m = 1; m < 64; m <<= 1) { s += __shfl_xor(s, m); s2 += __shfl_xor(s2, m); }
    __shared__ float red[8];
    int wid = threadIdx.x >> 6;
    if ((threadIdx.x & 63) == 0) { red[wid] = s; red[4 + wid] = s2; }
    __syncthreads();
    s  = red[0] + red[1] + red[2] + red[3];
    s2 = red[4] + red[5] + red[6] + red[7];
    float mu  = s * (1.0f / 1024.0f);
    float var = fmaxf(s2 * (1.0f / 1024.0f) - mu * mu, 0.0f);
    float rs  = rsqrtf(var + 1e-5f);
    float4 gv = ((const float4*)g)[threadIdx.x];
    float4 bv = ((const float4*)bt)[threadIdx.x];
    short4v o;
    o.x = f2bf((v.x - mu) * rs * gv.x + bv.x);
    o.y = f2bf((v.y - mu) * rs * gv.y + bv.y);
    o.z = f2bf((v.z - mu) * rs * gv.z + bv.z);
    o.w = f2bf((v.w - mu) * rs * gv.w + bv.w);
    *(short4v*)(out + (size_t)row * 1024 + (size_t)threadIdx.x * 4) = o;
}

// ---------------- GEMM: C[M,N] = A[M,K] * B[N,K]^T, bf16 in, fp32 acc ----------------
// MODE 0: bf16 out. MODE 1: fp32 out = acc + resid. MODE 2: bf16 out = gelu(acc).
// MODE 3: bf16 out = acc * osc.
template<int MODE>
__global__ __launch_bounds__(256) void gemm_bt(const short* __restrict__ A,
                                               const short* __restrict__ B,
                                               void* __restrict__ out,
                                               const float* __restrict__ resid,
                                               int M, int N, int K, float osc) {
    __shared__ short lA[2][128 * 32];
    __shared__ short lB[2][128 * 32];
    int tid = threadIdx.x;
    int nbn = N >> 7;
    int bm = blockIdx.x / nbn, bn = blockIdx.x % nbn;
    int row0 = bm << 7, col0 = bn << 7;
    int wid = tid >> 6, lane = tid & 63;
    int wm = wid >> 1, wn = wid & 1;
    int lr = lane & 15, lg = lane >> 4;

    f32x4 acc[4][4] = {};

    auto stage = [&](int buf, int kst) {
        const short* Ab = A + (size_t)row0 * K + kst * 32;
        const short* Bb = B + (size_t)col0 * K + kst * 32;
        #pragma unroll
        for (int c = 0; c < 2; ++c) {
            int idx = c * 256 + tid;
            int r = idx >> 2, sp = idx & 3;
            int sl = sp ^ ((r >> 1) & 3);
            gld16(Ab + (size_t)r * K + sl * 8, &lA[buf][idx * 8]);
            gld16(Bb + (size_t)r * K + sl * 8, &lB[buf][idx * 8]);
        }
    };

    int NK = K >> 5;
    stage(0, 0);
    __syncthreads();
    for (int ks = 0; ks < NK; ++ks) {
        int cur = ks & 1;
        if (ks + 1 < NK) stage(cur ^ 1, ks + 1);
        const short* pa = lA[cur];
        const short* pb = lB[cur];
        short8 af[4], bf[4];
        #pragma unroll
        for (int f = 0; f < 4; ++f) {
            int ra = wm * 64 + f * 16 + lr;
            af[f] = *(const short8*)(pa + ra * 32 + ((lg ^ ((ra >> 1) & 3)) << 3));
            int rb = wn * 64 + f * 16 + lr;
            bf[f] = *(const short8*)(pb + rb * 32 + ((lg ^ ((rb >> 1) & 3)) << 3));
        }
        #pragma unroll
        for (int i = 0; i < 4; ++i)
            #pragma unroll
            for (int j = 0; j < 4; ++j)
                MFMA(acc[i][j], af[i], bf[j]);
        __syncthreads();
    }
    asm volatile("s_nop 7\n\ts_nop 7");

    int orow0 = row0 + wm * 64, ocol0 = col0 + wn * 64;
    #pragma unroll
    for (int i = 0; i < 4; ++i)
        #pragma unroll
        for (int j = 0; j < 4; ++j)
            #pragma unroll
            for (int r = 0; r < 4; ++r) {
                int gr = orow0 + i * 16 + lg * 4 + r;
                int gc = ocol0 + j * 16 + lr;
                size_t off = (size_t)gr * N + gc;
                float v = acc[i][j][r];
                if constexpr (MODE == 0) {
                    ((short*)out)[off] = f2bf(v);
                } else if constexpr (MODE == 1) {
                    ((float*)out)[off] = v + resid[off];
                } else if constexpr (MODE == 2) {
                    float t = 0.5f * v * (1.0f + erff(v * 0.70710678118f));
                    ((short*)out)[off] = f2bf(t);
                } else {
                    ((short*)out)[off] = f2bf(v * osc);
                }
            }
}

// ---------------- Flash attention (swapped-QK^T, in-register softmax) ----------------
// Q pre-scaled by 0.125*log2(e). Scores computed as S^T = mfma(K, Q):
//   lane holds q = fm*16 + (lane&15); k = fn*16 + lg*4 + r  -> 16 k-values lane-local per fm.
__global__ __launch_bounds__(256) void attn(const short* __restrict__ Q,
                                            const short* __restrict__ K,
                                            const short* __restrict__ Vt,
                                            short* __restrict__ O) {
    __shared__ short lK[64 * 64];
    __shared__ short lV[64 * 64];
    __shared__ short lP[4][32 * 64];
    int tid = threadIdx.x;
    int qt = blockIdx.x & 15;
    int bh = blockIdx.x >> 4;
    int b = bh >> 4, h = bh & 15;
    int wid = tid >> 6, lane = tid & 63;
    int lr = lane & 15, lg = lane >> 4;
    int q0 = qt * 128 + wid * 32;

    short8 qf[2][2];
    #pragma unroll
    for (int fm = 0; fm < 2; ++fm)
        #pragma unroll
        for (int kb = 0; kb < 2; ++kb) {
            size_t roff = (size_t)(b * 2048 + q0 + fm * 16 + lr) * 1024 + h * 64 + kb * 32 + lg * 8;
            qf[fm][kb] = *(const short8*)(Q + roff);
        }

    f32x4 oacc[2][4] = {};
    float mrow[2] = { -1e30f, -1e30f };
    float lrs[2]  = { 0.0f, 0.0f };

    const short* Kb = K + (size_t)(b * 2048) * 1024 + h * 64;
    const short* Vb = Vt + (size_t)(h * 64) * 8192 + b * 2048;
    short* Pw = lP[wid];
    int albase = (lane & 48) >> 2;   // lg*4 : src lane for per-row broadcast

    for (int st = 0; st < 32; ++st) {
        #pragma unroll
        for (int c = 0; c < 2; ++c) {
            int idx = c * 256 + tid;
            int r = idx >> 3, sp = idx & 7;
            int sl = sp ^ (r & 7);
            gld16(Kb + (size_t)(st * 64 + r) * 1024 + sl * 8, &lK[idx * 8]);
            gld16(Vb + (size_t)r * 8192 + st * 64 + sl * 8, &lV[idx * 8]);
        }
        __syncthreads();

        // S^T = K * Q^T : sc2[fn][fm], rows k, cols q
        f32x4 sc2[4][2] = {};
        #pragma unroll
        for (int kb = 0; kb < 2; ++kb) {
            short8 kf[4];
            #pragma unroll
            for (int fn = 0; fn < 4; ++fn) {
                int kr = fn * 16 + lr;
                kf[fn] = *(const short8*)(lK + kr * 64 + (((kb * 4 + lg) ^ (kr & 7)) << 3));
            }
            #pragma unroll
            for (int fn = 0; fn < 4; ++fn)
                #pragma unroll
                for (int fm = 0; fm < 2; ++fm)
                    MFMA(sc2[fn][fm], kf[fn], qf[fm][kb]);
        }
        asm volatile("s_nop 7\n\ts_nop 7");

        #pragma unroll
        for (int fm = 0; fm < 2; ++fm) {
            // row max over 16 in-lane + 2 shuffles (across lg groups)
            float pm = sc2[0][fm][0];
            #pragma unroll
            for (int fn = 0; fn < 4; ++fn)
                #pragma unroll
                for (int r = 0; r < 4; ++r)
                    if (fn | r) pm = fmaxf(pm, sc2[fn][fm][r]);
            pm = fmaxf(pm, __shfl_xor(pm, 16));
            pm = fmaxf(pm, __shfl_xor(pm, 32));

            float mo = mrow[fm];
            float mn = mo;
            float al = 1.0f;
            if (!__all(pm <= mo + 8.0f)) {         // defer-max: rescale only on growth
                mn = fmaxf(mo, pm);
                al = exp2_hw(mo - mn);
                mrow[fm] = mn;
                #pragma unroll
                for (int r = 0; r < 4; ++r) {
                    float alr = __shfl(al, albase + r);   // al for q-row lg*4+r
                    #pragma unroll
                    for (int fn = 0; fn < 4; ++fn) oacc[fm][fn][r] *= alr;
                }
            }

            float p[4][4];
            float ps = 0.0f;
            #pragma unroll
            for (int fn = 0; fn < 4; ++fn)
                #pragma unroll
                for (int r = 0; r < 4; ++r) {
                    p[fn][r] = exp2_hw(sc2[fn][fm][r] - mn);
                    ps += p[fn][r];
                }
            ps += __shfl_xor(ps, 16);
            ps += __shfl_xor(ps, 32);
            lrs[fm] = lrs[fm] * al + ps;

            // write P row q=fm*16+lr: consecutive r = consecutive k -> b64 packed stores
            int pr = fm * 16 + lr;
            int swz = (pr & 7) << 3;
            #pragma unroll
            for (int fn = 0; fn < 4; ++fn) {
                uint2v w;
                w.x = cvt_pk_bf16(p[fn][0], p[fn][1]);
                w.y = cvt_pk_bf16(p[fn][2], p[fn][3]);
                *(uint2v*)(Pw + ((pr * 64 + fn * 16 + lg * 4) ^ swz)) = w;
            }
        }

        // O += P * V
        #pragma unroll
        for (int kb = 0; kb < 2; ++kb) {
            short8 pa[2], vf[4];
            #pragma unroll
            for (int fm = 0; fm < 2; ++fm) {
                int pr = fm * 16 + lr;
                pa[fm] = *(const short8*)(Pw + pr * 64 + (((kb * 4 + lg) ^ (pr & 7)) << 3));
            }
            #pragma unroll
            for (int fn = 0; fn < 4; ++fn) {
                int vr = fn * 16 + lr;
                vf[fn] = *(const short8*)(lV + vr * 64 + (((kb * 4 + lg) ^ (vr & 7)) << 3));
            }
            #pragma unroll
            for (int fm = 0; fm < 2; ++fm)
                #pragma unroll
                for (int fn = 0; fn < 4; ++fn)
                    MFMA(oacc[fm][fn], pa[fm], vf[fn]);
        }
        __syncthreads();
    }
    asm volatile("s_nop 7\n\ts_nop 7");

    #pragma unroll
    for (int fm = 0; fm < 2; ++fm)
        #pragma unroll
        for (int r = 0; r < 4; ++r) {
            float linv = __shfl(lrs[fm], albase + r);   // l for q-row lg*4+r
            float inv = 1.0f / linv;
            #pragma unroll
            for (int fn = 0; fn < 4; ++fn) {
                size_t off = (size_t)(b * 2048 + q0 + fm * 16 + lg * 4 + r) * 1024 + h * 64 + fn * 16 + lr;
                O[off] = f2bf(oacc[fm][fn][r] * inv);
            }
        }
}

// ---------------- launch ----------------
extern "C" void kernel_launch(void* const* d_in, const int* in_sizes, int n_in,
                              void* d_out, int out_size, void* d_ws, size_t ws_size,
                              hipStream_t stream) {
    const float* x   = (const float*)d_in[0];
    const float* ctx = (const float*)d_in[1];
    const float* Wq  = (const float*)d_in[2];
    const float* Wk  = (const float*)d_in[3];
    const float* Wv  = (const float*)d_in[4];
    const float* Wo  = (const float*)d_in[5];
    const float* W1  = (const float*)d_in[6];
    const float* W2  = (const float*)d_in[7];
    const float* g1  = (const float*)d_in[8];
    const float* b1  = (const float*)d_in[9];
    const float* gc  = (const float*)d_in[10];
    const float* bc  = (const float*)d_in[11];
    const float* g2  = (const float*)d_in[12];
    const float* b2  = (const float*)d_in[13];

    char* ws = (char*)d_ws;
    const size_t OFF_W  = 0;
    const size_t OFF_XN = 25165824;
    const size_t OFF_CN = OFF_XN + 16777216;
    const size_t OFF_QB = OFF_CN + 16777216;
    const size_t OFF_KB = OFF_QB + 16777216;
    const size_t OFF_VT = OFF_KB + 16777216;
    const size_t OFF_X2 = OFF_VT + 16777216;
    const size_t OFF_F1 = OFF_X2 + 33554432;

    short* Wb = (short*)(ws + OFF_W);
    short* XN = (short*)(ws + OFF_XN);
    short* CN = (short*)(ws + OFF_CN);
    short* QB = (short*)(ws + OFF_QB);
    short* KB = (short*)(ws + OFF_KB);
    short* VT = (short*)(ws + OFF_VT);
    float* X2 = (float*)(ws + OFF_X2);
    short* F1 = (short*)(ws + OFF_F1);
    short* OB = XN;
    short* H  = CN;

    const size_t WQo = 0, WKo = 1048576, WVo = 2097152, WOo = 3145728;
    const size_t W1o = 4194304, W2o = 8388608;
    const float QSCALE = 0.125f * 1.4426950408889634f;   // fold softmax scale + log2(e) into Q

    cvt_weights<<<12288, 256, 0, stream>>>(Wq, Wk, Wv, Wo, W1, W2, Wb);
    ln_bf16<<<8192, 256, 0, stream>>>(x, g1, b1, XN);
    ln_bf16<<<8192, 256, 0, stream>>>(ctx, gc, bc, CN);
    gemm_bt<3><<<512, 256, 0, stream>>>(XN, Wb + WQo, QB, nullptr, 8192, 1024, 1024, QSCALE);
    gemm_bt<0><<<512, 256, 0, stream>>>(CN, Wb + WKo, KB, nullptr, 8192, 1024, 1024, 1.0f);
    gemm_bt<0><<<512, 256, 0, stream>>>(Wb + WVo, CN, VT, nullptr, 1024, 8192, 1024, 1.0f);
    attn<<<1024, 256, 0, stream>>>(QB, KB, VT, OB);
    gemm_bt<1><<<512, 256, 0, stream>>>(OB, Wb + WOo, X2, x, 8192, 1024, 1024, 1.0f);
    ln_bf16<<<8192, 256, 0, stream>>>(X2, g2, b2, H);
    gemm_bt<2><<<2048, 256, 0, stream>>>(H, Wb + W1o, F1, nullptr, 8192, 4096, 1024, 1.0f);
    gemm_bt<1><<<512, 256, 0, stream>>>(F1, Wb + W2o, (float*)d_out, X2, 8192, 1024, 4096, 1.0f);
}

// Round 3
// 474.845 us; speedup vs baseline: 1.2390x; 1.0320x over previous
//
#include <hip/hip_runtime.h>
#include <cstdint>
#include <cstddef>

typedef __attribute__((ext_vector_type(8))) short short8;
typedef __attribute__((ext_vector_type(4))) short short4v;
typedef __attribute__((ext_vector_type(4))) float f32x4;
typedef __attribute__((ext_vector_type(2))) unsigned uint2v;

#define DEV static __device__ __forceinline__

DEV short f2bf(float f) {
    unsigned u = __builtin_bit_cast(unsigned, f);
    unsigned r = (u + 0x7fffu + ((u >> 16) & 1u)) >> 16;
    return (short)r;
}

DEV unsigned cvt_pk_bf16(float a, float b) {
    unsigned r;
    asm("v_cvt_pk_bf16_f32 %0, %1, %2" : "=v"(r) : "v"(a), "v"(b));
    return r;
}

DEV float exp2_hw(float x) {
    float r;
    asm("v_exp_f32 %0, %1" : "=v"(r) : "v"(x));
    return r;
}

DEV void gld16(const void* g, void* l) {
    __builtin_amdgcn_global_load_lds((const __attribute__((address_space(1))) void*)g,
                                     (__attribute__((address_space(3))) void*)l, 16, 0, 0);
}

#define MFMA(c, a, b) asm volatile("v_mfma_f32_16x16x32_bf16 %0, %1, %2, %0" : "+v"(c) : "v"(a), "v"(b))
#define BAR() asm volatile("s_barrier" ::: "memory")

// ---------------- weight fp32 -> bf16 convert ----------------
__global__ __launch_bounds__(256) void cvt_weights(
    const float* __restrict__ wq, const float* __restrict__ wk,
    const float* __restrict__ wv, const float* __restrict__ wo,
    const float* __restrict__ w1, const float* __restrict__ w2,
    short* __restrict__ dst) {
    long long gid = (long long)blockIdx.x * 256 + threadIdx.x;
    long long i4 = gid * 4;
    const float* src; long long loc;
    if (i4 < (4LL << 20)) {
        int s = (int)(i4 >> 20);
        src = (s == 0) ? wq : (s == 1) ? wk : (s == 2) ? wv : wo;
        loc = i4 & ((1LL << 20) - 1);
    } else {
        long long r = i4 - (4LL << 20);
        int s = (int)(r >> 22);
        src = s ? w2 : w1;
        loc = r & ((1LL << 22) - 1);
    }
    float4 v = *(const float4*)(src + loc);
    short4v o;
    o.x = f2bf(v.x); o.y = f2bf(v.y); o.z = f2bf(v.z); o.w = f2bf(v.w);
    *(short4v*)(dst + i4) = o;
}

// ---------------- LayerNorm (D=1024), fp32 in -> bf16 out ----------------
__global__ __launch_bounds__(256) void ln_bf16(const float* __restrict__ x,
                                               const float* __restrict__ g,
                                               const float* __restrict__ bt,
                                               short* __restrict__ out) {
    int row = blockIdx.x;
    const float4* xr = (const float4*)(x + (size_t)row * 1024);
    float4 v = xr[threadIdx.x];
    float s  = v.x + v.y + v.z + v.w;
    float s2 = v.x*v.x + v.y*v.y + v.z*v.z + v.w*v.w;
    #pragma unroll
    for (int m = 1; m < 64; m <<= 1) { s += __shfl_xor(s, m); s2 += __shfl_xor(s2, m); }
    __shared__ float red[8];
    int wid = threadIdx.x >> 6;
    if ((threadIdx.x & 63) == 0) { red[wid] = s; red[4 + wid] = s2; }
    __syncthreads();
    s  = red[0] + red[1] + red[2] + red[3];
    s2 = red[4] + red[5] + red[6] + red[7];
    float mu  = s * (1.0f / 1024.0f);
    float var = fmaxf(s2 * (1.0f / 1024.0f) - mu * mu, 0.0f);
    float rs  = rsqrtf(var + 1e-5f);
    float4 gv = ((const float4*)g)[threadIdx.x];
    float4 bv = ((const float4*)bt)[threadIdx.x];
    short4v o;
    o.x = f2bf((v.x - mu) * rs * gv.x + bv.x);
    o.y = f2bf((v.y - mu) * rs * gv.y + bv.y);
    o.z = f2bf((v.z - mu) * rs * gv.z + bv.z);
    o.w = f2bf((v.w - mu) * rs * gv.w + bv.w);
    *(short4v*)(out + (size_t)row * 1024 + (size_t)threadIdx.x * 4) = o;
}

// ---------------- Phased GEMM: C[M,N] = A[M,K]*B[N,K]^T, bf16 in, fp32 acc ----------------
// BM=256 BN=128 BK=32, 4 waves (2Mx2N), wave tile 128x64 (8x4 frags).
// Triple-buffered LDS (72KB -> 2 blocks/CU), prefetch distance 2, counted vmcnt(6).
// MODE 0: bf16 out. MODE 1: fp32 out = acc+resid. MODE 2: bf16 gelu. MODE 3: bf16 *osc.
template<int MODE>
__global__ __launch_bounds__(256, 2) void gemm8(const short* __restrict__ A,
                                                const short* __restrict__ B,
                                                void* __restrict__ out,
                                                const float* __restrict__ resid,
                                                int M, int N, int K, float osc) {
    __shared__ short lds[3 * 12288];   // per buf: A 256x32 (8192) | B 128x32 (4096)
    const int tid = threadIdx.x;
    const int nbn = N >> 7;
    // bijective XCD swizzle (grid always % 8 == 0 here)
    int cpx = gridDim.x >> 3;
    int swz = (blockIdx.x & 7) * cpx + (blockIdx.x >> 3);
    int bm = swz / nbn, bn = swz % nbn;
    const int row0 = bm << 8, col0 = bn << 7;
    const int wid = tid >> 6, lane = tid & 63;
    const int wm = wid >> 1, wn = wid & 1;
    const int lr = lane & 15, lg = lane >> 4;

    // stage half h of tile kt into buffer at element offset bb (3 gld16 per thread per half)
    auto stage = [&](int kt, int bb, int h) {
        const short* Ab = A + (size_t)row0 * K + kt * 32;
        const short* Bb = B + (size_t)col0 * K + kt * 32;
        #pragma unroll
        for (int l = 0; l < 2; ++l) {
            int g = (h * 2 + l) * 256 + tid;             // A: g in 0..1023
            int r = g >> 2;
            int sl = (g & 3) ^ ((r >> 1) & 3);
            gld16(Ab + (size_t)r * K + sl * 8, &lds[bb + g * 8]);
        }
        {
            int g = h * 256 + tid;                        // B: g in 0..511
            int r = g >> 2;
            int sl = (g & 3) ^ ((r >> 1) & 3);
            gld16(Bb + (size_t)r * K + sl * 8, &lds[bb + 8192 + g * 8]);
        }
    };

    f32x4 acc[8][4] = {};
    const int NK = K >> 5;

    // prologue: stage tiles 0 and 1
    stage(0, 0, 0);     stage(0, 0, 1);
    stage(1, 12288, 0); stage(1, 12288, 1);
    asm volatile("s_waitcnt vmcnt(6)" ::: "memory");
    BAR();

    int cb = 0, sb = 2;                 // current buf idx, stage buf idx (kt+2)
    const int rsw = ((lr >> 1) & 3);
    short8 bfr[4];
    for (int kt = 0; kt < NK; ++kt) {
        int bb = cb * 12288, sbb = sb * 12288;
        bool st = (kt + 2) < NK;
        #pragma unroll
        for (int p = 0; p < 2; ++p) {
            short8 af[4];
            int csw = (lg ^ rsw) << 3;
            #pragma unroll
            for (int i = 0; i < 4; ++i)
                af[i] = *(const short8*)(lds + bb + (wm * 128 + (p * 4 + i) * 16 + lr) * 32 + csw);
            if (p == 0) {
                #pragma unroll
                for (int j = 0; j < 4; ++j)
                    bfr[j] = *(const short8*)(lds + bb + 8192 + (wn * 64 + j * 16 + lr) * 32 + csw);
            }
            if (st) stage(kt + 2, sbb, p);
            BAR();
            __builtin_amdgcn_s_setprio(1);
            #pragma unroll
            for (int i = 0; i < 4; ++i)
                #pragma unroll
                for (int j = 0; j < 4; ++j)
                    MFMA(acc[p * 4 + i][j], af[i], bfr[j]);
            __builtin_amdgcn_s_setprio(0);
            if (p == 1) {
                if (st) asm volatile("s_waitcnt vmcnt(6)" ::: "memory");
                else    asm volatile("s_waitcnt vmcnt(0)" ::: "memory");
            }
            BAR();
        }
        cb = (cb == 2) ? 0 : cb + 1;
        sb = (sb == 2) ? 0 : sb + 1;
    }
    asm volatile("s_nop 7\n\ts_nop 7");

    int orow0 = row0 + wm * 128, ocol0 = col0 + wn * 64;
    #pragma unroll
    for (int i = 0; i < 8; ++i)
        #pragma unroll
        for (int j = 0; j < 4; ++j)
            #pragma unroll
            for (int r = 0; r < 4; ++r) {
                int gr = orow0 + i * 16 + lg * 4 + r;
                int gc = ocol0 + j * 16 + lr;
                size_t off = (size_t)gr * N + gc;
                float v = acc[i][j][r];
                if constexpr (MODE == 0) {
                    ((short*)out)[off] = f2bf(v);
                } else if constexpr (MODE == 1) {
                    ((float*)out)[off] = v + resid[off];
                } else if constexpr (MODE == 2) {
                    float t = 0.5f * v * (1.0f + erff(v * 0.70710678118f));
                    ((short*)out)[off] = f2bf(t);
                } else {
                    ((short*)out)[off] = f2bf(v * osc);
                }
            }
}

// ---------------- Flash attention (swapped-QK^T, in-register softmax) ----------------
__global__ __launch_bounds__(256) void attn(const short* __restrict__ Q,
                                            const short* __restrict__ K,
                                            const short* __restrict__ Vt,
                                            short* __restrict__ O) {
    __shared__ short lK[64 * 64];
    __shared__ short lV[64 * 64];
    __shared__ short lP[4][32 * 64];
    int tid = threadIdx.x;
    int qt = blockIdx.x & 15;
    int bh = blockIdx.x >> 4;
    int b = bh >> 4, h = bh & 15;
    int wid = tid >> 6, lane = tid & 63;
    int lr = lane & 15, lg = lane >> 4;
    int q0 = qt * 128 + wid * 32;

    short8 qf[2][2];
    #pragma unroll
    for (int fm = 0; fm < 2; ++fm)
        #pragma unroll
        for (int kb = 0; kb < 2; ++kb) {
            size_t roff = (size_t)(b * 2048 + q0 + fm * 16 + lr) * 1024 + h * 64 + kb * 32 + lg * 8;
            qf[fm][kb] = *(const short8*)(Q + roff);
        }

    f32x4 oacc[2][4] = {};
    float mrow[2] = { -1e30f, -1e30f };
    float lrs[2]  = { 0.0f, 0.0f };

    const short* Kb = K + (size_t)(b * 2048) * 1024 + h * 64;
    const short* Vb = Vt + (size_t)(h * 64) * 8192 + b * 2048;
    short* Pw = lP[wid];
    int albase = (lane & 48) >> 2;

    for (int st = 0; st < 32; ++st) {
        #pragma unroll
        for (int c = 0; c < 2; ++c) {
            int idx = c * 256 + tid;
            int r = idx >> 3, sp = idx & 7;
            int sl = sp ^ (r & 7);
            gld16(Kb + (size_t)(st * 64 + r) * 1024 + sl * 8, &lK[idx * 8]);
            gld16(Vb + (size_t)r * 8192 + st * 64 + sl * 8, &lV[idx * 8]);
        }
        __syncthreads();

        f32x4 sc2[4][2] = {};
        #pragma unroll
        for (int kb = 0; kb < 2; ++kb) {
            short8 kf[4];
            #pragma unroll
            for (int fn = 0; fn < 4; ++fn) {
                int kr = fn * 16 + lr;
                kf[fn] = *(const short8*)(lK + kr * 64 + (((kb * 4 + lg) ^ (kr & 7)) << 3));
            }
            #pragma unroll
            for (int fn = 0; fn < 4; ++fn)
                #pragma unroll
                for (int fm = 0; fm < 2; ++fm)
                    MFMA(sc2[fn][fm], kf[fn], qf[fm][kb]);
        }
        asm volatile("s_nop 7\n\ts_nop 7");

        #pragma unroll
        for (int fm = 0; fm < 2; ++fm) {
            float pm = sc2[0][fm][0];
            #pragma unroll
            for (int fn = 0; fn < 4; ++fn)
                #pragma unroll
                for (int r = 0; r < 4; ++r)
                    if (fn | r) pm = fmaxf(pm, sc2[fn][fm][r]);
            pm = fmaxf(pm, __shfl_xor(pm, 16));
            pm = fmaxf(pm, __shfl_xor(pm, 32));

            float mo = mrow[fm];
            float mn = mo;
            float al = 1.0f;
            if (!__all(pm <= mo + 8.0f)) {
                mn = fmaxf(mo, pm);
                al = exp2_hw(mo - mn);
                mrow[fm] = mn;
                #pragma unroll
                for (int r = 0; r < 4; ++r) {
                    float alr = __shfl(al, albase + r);
                    #pragma unroll
                    for (int fn = 0; fn < 4; ++fn) oacc[fm][fn][r] *= alr;
                }
            }

            float p[4][4];
            float ps = 0.0f;
            #pragma unroll
            for (int fn = 0; fn < 4; ++fn)
                #pragma unroll
                for (int r = 0; r < 4; ++r) {
                    p[fn][r] = exp2_hw(sc2[fn][fm][r] - mn);
                    ps += p[fn][r];
                }
            ps += __shfl_xor(ps, 16);
            ps += __shfl_xor(ps, 32);
            lrs[fm] = lrs[fm] * al + ps;

            int pr = fm * 16 + lr;
            int swz = (pr & 7) << 3;
            #pragma unroll
            for (int fn = 0; fn < 4; ++fn) {
                uint2v w;
                w.x = cvt_pk_bf16(p[fn][0], p[fn][1]);
                w.y = cvt_pk_bf16(p[fn][2], p[fn][3]);
                *(uint2v*)(Pw + ((pr * 64 + fn * 16 + lg * 4) ^ swz)) = w;
            }
        }

        #pragma unroll
        for (int kb = 0; kb < 2; ++kb) {
            short8 pa[2], vf[4];
            #pragma unroll
            for (int fm = 0; fm < 2; ++fm) {
                int pr = fm * 16 + lr;
                pa[fm] = *(const short8*)(Pw + pr * 64 + (((kb * 4 + lg) ^ (pr & 7)) << 3));
            }
            #pragma unroll
            for (int fn = 0; fn < 4; ++fn) {
                int vr = fn * 16 + lr;
                vf[fn] = *(const short8*)(lV + vr * 64 + (((kb * 4 + lg) ^ (vr & 7)) << 3));
            }
            #pragma unroll
            for (int fm = 0; fm < 2; ++fm)
                #pragma unroll
                for (int fn = 0; fn < 4; ++fn)
                    MFMA(oacc[fm][fn], pa[fm], vf[fn]);
        }
        __syncthreads();
    }
    asm volatile("s_nop 7\n\ts_nop 7");

    #pragma unroll
    for (int fm = 0; fm < 2; ++fm)
        #pragma unroll
        for (int r = 0; r < 4; ++r) {
            float linv = __shfl(lrs[fm], albase + r);
            float inv = 1.0f / linv;
            #pragma unroll
            for (int fn = 0; fn < 4; ++fn) {
                size_t off = (size_t)(b * 2048 + q0 + fm * 16 + lg * 4 + r) * 1024 + h * 64 + fn * 16 + lr;
                O[off] = f2bf(oacc[fm][fn][r] * inv);
            }
        }
}

// ---------------- launch ----------------
extern "C" void kernel_launch(void* const* d_in, const int* in_sizes, int n_in,
                              void* d_out, int out_size, void* d_ws, size_t ws_size,
                              hipStream_t stream) {
    const float* x   = (const float*)d_in[0];
    const float* ctx = (const float*)d_in[1];
    const float* Wq  = (const float*)d_in[2];
    const float* Wk  = (const float*)d_in[3];
    const float* Wv  = (const float*)d_in[4];
    const float* Wo  = (const float*)d_in[5];
    const float* W1  = (const float*)d_in[6];
    const float* W2  = (const float*)d_in[7];
    const float* g1  = (const float*)d_in[8];
    const float* b1  = (const float*)d_in[9];
    const float* gc  = (const float*)d_in[10];
    const float* bc  = (const float*)d_in[11];
    const float* g2  = (const float*)d_in[12];
    const float* b2  = (const float*)d_in[13];

    char* ws = (char*)d_ws;
    const size_t OFF_W  = 0;
    const size_t OFF_XN = 25165824;
    const size_t OFF_CN = OFF_XN + 16777216;
    const size_t OFF_QB = OFF_CN + 16777216;
    const size_t OFF_KB = OFF_QB + 16777216;
    const size_t OFF_VT = OFF_KB + 16777216;
    const size_t OFF_X2 = OFF_VT + 16777216;
    const size_t OFF_F1 = OFF_X2 + 33554432;

    short* Wb = (short*)(ws + OFF_W);
    short* XN = (short*)(ws + OFF_XN);
    short* CN = (short*)(ws + OFF_CN);
    short* QB = (short*)(ws + OFF_QB);
    short* KB = (short*)(ws + OFF_KB);
    short* VT = (short*)(ws + OFF_VT);
    float* X2 = (float*)(ws + OFF_X2);
    short* F1 = (short*)(ws + OFF_F1);
    short* OB = XN;
    short* H  = CN;

    const size_t WQo = 0, WKo = 1048576, WVo = 2097152, WOo = 3145728;
    const size_t W1o = 4194304, W2o = 8388608;
    const float QSCALE = 0.125f * 1.4426950408889634f;

    cvt_weights<<<12288, 256, 0, stream>>>(Wq, Wk, Wv, Wo, W1, W2, Wb);
    ln_bf16<<<8192, 256, 0, stream>>>(x, g1, b1, XN);
    ln_bf16<<<8192, 256, 0, stream>>>(ctx, gc, bc, CN);
    gemm8<3><<<256, 256, 0, stream>>>(XN, Wb + WQo, QB, nullptr, 8192, 1024, 1024, QSCALE);
    gemm8<0><<<256, 256, 0, stream>>>(CN, Wb + WKo, KB, nullptr, 8192, 1024, 1024, 1.0f);
    gemm8<0><<<256, 256, 0, stream>>>(Wb + WVo, CN, VT, nullptr, 1024, 8192, 1024, 1.0f);
    attn<<<1024, 256, 0, stream>>>(QB, KB, VT, OB);
    gemm8<1><<<256, 256, 0, stream>>>(OB, Wb + WOo, X2, x, 8192, 1024, 1024, 1.0f);
    ln_bf16<<<8192, 256, 0, stream>>>(X2, g2, b2, H);
    gemm8<2><<<1024, 256, 0, stream>>>(H, Wb + W1o, F1, nullptr, 8192, 4096, 1024, 1.0f);
    gemm8<1><<<256, 256, 0, stream>>>(F1, Wb + W2o, (float*)d_out, X2, 8192, 1024, 4096, 1.0f);
}